// Round 7
// baseline (110.680 us; speedup 1.0000x reference)
//
#include <hip/hip_runtime.h>
#include <hip/hip_fp16.h>

typedef _Float16 f16;

// ---------------- one-time LUT build: g_ty(x) on a uniform grid ----------------
// ONE THREAD PER TABLE ROW. Fully serial, fully unrolled, no cross-lane ops:
// obviously-correct reference builder (weights via uniform-address scalar loads).
__global__ __launch_bounds__(256)
void build_table(const float* __restrict__ w00, const float* __restrict__ b00,
                 const float* __restrict__ w01, const float* __restrict__ b01,
                 const float* __restrict__ w02, const float* __restrict__ b02,
                 const float* __restrict__ w10, const float* __restrict__ b10,
                 const float* __restrict__ w11, const float* __restrict__ b11,
                 const float* __restrict__ w12, const float* __restrict__ b12,
                 f16* __restrict__ tab, int nseg, float xmin, float h)
{
    const int row  = blockIdx.x * 256 + threadIdx.x;
    const int rows = nseg + 1;
    if (row >= 2 * rows) return;
    const int ty = (row >= rows) ? 1 : 0;
    const int i  = ty ? (row - rows) : row;
    const float x = __builtin_fmaf((float)i, h, xmin);

    const float* __restrict__ W0 = ty ? w10 : w00;
    const float* __restrict__ B0 = ty ? b10 : b00;
    const float* __restrict__ W1 = ty ? w11 : w01;
    const float* __restrict__ B1 = ty ? b11 : b01;
    const float* __restrict__ W2 = ty ? w12 : w02;
    const float* __restrict__ B2 = ty ? b12 : b02;

    float h0[24];
#pragma unroll
    for (int j = 0; j < 24; ++j)
        h0[j] = tanhf(__builtin_fmaf(x, W0[j], B0[j]));

    float h1[48];
#pragma unroll
    for (int k = 0; k < 48; ++k) {
        float a = B1[k];
#pragma unroll
        for (int j = 0; j < 24; ++j)
            a = __builtin_fmaf(h0[j], W1[j * 48 + k], a);
        h1[k] = tanhf(a) + h0[(k < 24) ? k : (k - 24)];
    }

#pragma unroll
    for (int e = 0; e < 96; ++e) {
        float a = B2[e];
#pragma unroll
        for (int k = 0; k < 48; ++k)
            a = __builtin_fmaf(h1[k], W2[k * 96 + e], a);
        tab[(size_t)row * 96 + e] = (f16)(tanhf(a) + h1[(e < 48) ? e : (e - 48)]);
    }
}

// ---------------- main: lerp LUT + fused dd-contraction, all in registers ----------------
// rows r: 0..45 type0 (s=r), 46/47 pad; 48..139 type1 (s=r-2), 140..143 pad.
// 9 row-tiles of 16; wave w (of 3) owns tiles {w, w+3, w+6}.
// lane = (lhi, l15): lhi*4+rg = row-in-tile, l15 = e-pair index (e = c*32 + 2*l15 + {0,1}).
__global__ __launch_bounds__(192, 4)
void emb_main(const float* __restrict__ dmat, const f16* __restrict__ tab,
              int nseg, float scale, float offs,
              float* __restrict__ out)
{
    __shared__ float DD[144 * 4];       // [r][4] f32, pads zero (wave-private fill/use)
    __shared__ float Y2s[3 * 4 * 96];   // per-wave Y partials [w][d][e]

    const int tid = threadIdx.x, n = blockIdx.x;
    const int w = tid >> 6, lane = tid & 63;
    const int l15 = lane & 15, lhi = lane >> 4;

    // DD fill: wave w fills the 48 rows of its own 3 tiles
    if (lane < 48) {
        const int t = w + 3 * (lane >> 4);
        const int r = t * 16 + (lane & 15);
        const bool t0 = (t < 3);
        const int  s  = t0 ? r : (r - 2);
        const bool ok = t0 ? (r < 46) : (r < 140);
        float4 v = make_float4(0.f, 0.f, 0.f, 0.f);
        if (ok) v = *reinterpret_cast<const float4*>(dmat + (size_t)n * 552 + s * 4);
        *reinterpret_cast<float4*>(&DD[r * 4]) = v;
    }

    float yp[24];                        // [c][ep][d]
#pragma unroll
    for (int i = 0; i < 24; ++i) yp[i] = 0.f;

    const float clampHi = (float)nseg - 0.5f;
    const int rowU32 = 48;               // 96 halves per table row

    for (int t = w; t < 9; t += 3) {
        const int tyt = (t >= 3);
        const uint32_t* __restrict__ tb =
            reinterpret_cast<const uint32_t*>(tab + (size_t)tyt * (nseg + 1) * 96);

        int irow[4]; float fr[4]; float4 dd4[4];
#pragma unroll
        for (int rg = 0; rg < 4; ++rg) {
            const int r = t * 16 + lhi * 4 + rg;
            const float x = DD[r * 4];                    // 16-lane LDS broadcast
            float u = __builtin_fmaf(x, scale, offs);
            u = fminf(fmaxf(u, 0.f), clampHi);
            const int i = (int)u;
            irow[rg] = i * rowU32;
            fr[rg]   = u - (float)i;
            dd4[rg]  = *reinterpret_cast<const float4*>(&DD[r * 4]);
        }

#pragma unroll
        for (int c = 0; c < 3; ++c) {
#pragma unroll
            for (int rg = 0; rg < 4; ++rg) {
                const uint32_t* p = tb + irow[rg] + c * 16 + l15;
                const uint32_t alo = p[0];                 // row i,  e-pair
                const uint32_t ahi = p[rowU32];            // row i+1, e-pair
                const __half2 lo2 = *reinterpret_cast<const __half2*>(&alo);
                const __half2 hi2 = *reinterpret_cast<const __half2*>(&ahi);
                const float2 lo = __half22float2(lo2);
                const float2 hi = __half22float2(hi2);
                const float g0 = __builtin_fmaf(fr[rg], hi.x - lo.x, lo.x);
                const float g1 = __builtin_fmaf(fr[rg], hi.y - lo.y, lo.y);
                const int b = c * 8;
                yp[b + 0] = __builtin_fmaf(dd4[rg].x, g0, yp[b + 0]);
                yp[b + 1] = __builtin_fmaf(dd4[rg].y, g0, yp[b + 1]);
                yp[b + 2] = __builtin_fmaf(dd4[rg].z, g0, yp[b + 2]);
                yp[b + 3] = __builtin_fmaf(dd4[rg].w, g0, yp[b + 3]);
                yp[b + 4] = __builtin_fmaf(dd4[rg].x, g1, yp[b + 4]);
                yp[b + 5] = __builtin_fmaf(dd4[rg].y, g1, yp[b + 5]);
                yp[b + 6] = __builtin_fmaf(dd4[rg].z, g1, yp[b + 6]);
                yp[b + 7] = __builtin_fmaf(dd4[rg].w, g1, yp[b + 7]);
            }
        }
    }

    // reduce over the 4 lhi row-groups
#pragma unroll
    for (int i = 0; i < 24; ++i) {
        float v = yp[i];
        v += __shfl_xor(v, 16);
        v += __shfl_xor(v, 32);
        yp[i] = v;
    }
    if (lhi == 0) {
#pragma unroll
        for (int c = 0; c < 3; ++c)
#pragma unroll
            for (int d = 0; d < 4; ++d) {
                const float2 v2 = make_float2(yp[c * 8 + d], yp[c * 8 + 4 + d]);
                *reinterpret_cast<float2*>(&Y2s[w * 384 + d * 96 + c * 32 + 2 * l15]) = v2;
            }
    }
    __syncthreads();

    // stage 4: xs = (sum_w Y)/138; res[e][k] = sum_d xs[d][e]*xs[d][k]
    if (tid < 96) {
        constexpr float inv = 1.0f / 138.0f;
        const float x0 = (Y2s[tid]       + Y2s[384 + tid]       + Y2s[768 + tid])       * inv;
        const float x1 = (Y2s[96 + tid]  + Y2s[384 + 96 + tid]  + Y2s[768 + 96 + tid])  * inv;
        const float x2 = (Y2s[192 + tid] + Y2s[384 + 192 + tid] + Y2s[768 + 192 + tid]) * inv;
        const float x3 = (Y2s[288 + tid] + Y2s[384 + 288 + tid] + Y2s[768 + 288 + tid]) * inv;
        float rv[8];
#pragma unroll
        for (int k = 0; k < 8; ++k) {   // same-address reads -> LDS broadcast
            const float k0 = (Y2s[k]       + Y2s[384 + k]       + Y2s[768 + k])       * inv;
            const float k1 = (Y2s[96 + k]  + Y2s[384 + 96 + k]  + Y2s[768 + 96 + k])  * inv;
            const float k2 = (Y2s[192 + k] + Y2s[384 + 192 + k] + Y2s[768 + 192 + k]) * inv;
            const float k3 = (Y2s[288 + k] + Y2s[384 + 288 + k] + Y2s[768 + 288 + k]) * inv;
            float rr = x0 * k0;
            rr = __builtin_fmaf(x1, k1, rr);
            rr = __builtin_fmaf(x2, k2, rr);
            rr = __builtin_fmaf(x3, k3, rr);
            rv[k] = rr;
        }
        float* op = out + (size_t)n * 768 + tid * 8;
        *reinterpret_cast<float4*>(op)     = make_float4(rv[0], rv[1], rv[2], rv[3]);
        *reinterpret_cast<float4*>(op + 4) = make_float4(rv[4], rv[5], rv[6], rv[7]);
    }
}

extern "C" void kernel_launch(void* const* d_in, const int* in_sizes, int n_in,
                              void* d_out, int out_size, void* d_ws, size_t ws_size,
                              hipStream_t stream)
{
    const float* dmat = (const float*)d_in[0];
    const int n_atoms = in_sizes[0] / 552;   // 6144

    // largest table that fits ws: 2 types x (nseg+1) rows x 96 f16 (never overflows ws)
    int nseg = 2048;
    while ((size_t)2 * (size_t)(nseg + 1) * 96 * sizeof(f16) > ws_size && nseg > 16)
        nseg >>= 1;
    const float xmin = -8.f, xmax = 8.f;
    const float h     = (xmax - xmin) / (float)nseg;
    const float scale = (float)nseg / (xmax - xmin);
    const float offs  = -xmin * scale;
    f16* tab = (f16*)d_ws;

    const int rows2 = 2 * (nseg + 1);
    build_table<<<(rows2 + 255) / 256, 256, 0, stream>>>(
        (const float*)d_in[1],  (const float*)d_in[2],
        (const float*)d_in[3],  (const float*)d_in[4],
        (const float*)d_in[5],  (const float*)d_in[6],
        (const float*)d_in[7],  (const float*)d_in[8],
        (const float*)d_in[9],  (const float*)d_in[10],
        (const float*)d_in[11], (const float*)d_in[12],
        tab, nseg, xmin, h);

    emb_main<<<n_atoms, 192, 0, stream>>>(dmat, tab, nseg, scale, offs, (float*)d_out);
}

// Round 8
// 40.967 us; speedup vs baseline: 2.7017x; 2.7017x over previous
//
#include <hip/hip_runtime.h>
#include <hip/hip_fp16.h>

typedef _Float16 f16;

// ---------------- one-time LUT build: g_ty(x) on a uniform grid ----------------
// ONE BLOCK (128 threads) PER TABLE ROW. Layer parallelism via LDS + barriers —
// no cross-lane shuffles (R6's failure mode), exact f32 tanhf MLP.
__global__ __launch_bounds__(128)
void build_table(const float* __restrict__ w00, const float* __restrict__ b00,
                 const float* __restrict__ w01, const float* __restrict__ b01,
                 const float* __restrict__ w02, const float* __restrict__ b02,
                 const float* __restrict__ w10, const float* __restrict__ b10,
                 const float* __restrict__ w11, const float* __restrict__ b11,
                 const float* __restrict__ w12, const float* __restrict__ b12,
                 f16* __restrict__ tab, int nseg, float xmin, float h)
{
    __shared__ float h0s[24];
    __shared__ float h1s[48];

    const int row  = blockIdx.x;
    const int rows = nseg + 1;
    const int ty   = (row >= rows) ? 1 : 0;
    const int i    = ty ? (row - rows) : row;
    const float x  = __builtin_fmaf((float)i, h, xmin);
    const int tid  = threadIdx.x;

    const float* __restrict__ W0 = ty ? w10 : w00;
    const float* __restrict__ B0 = ty ? b10 : b00;
    const float* __restrict__ W1 = ty ? w11 : w01;
    const float* __restrict__ B1 = ty ? b11 : b01;
    const float* __restrict__ W2 = ty ? w12 : w02;
    const float* __restrict__ B2 = ty ? b12 : b02;

    if (tid < 24)
        h0s[tid] = tanhf(__builtin_fmaf(x, W0[tid], B0[tid]));
    __syncthreads();

    if (tid < 48) {
        float a = B1[tid];
#pragma unroll
        for (int j = 0; j < 24; ++j)
            a = __builtin_fmaf(h0s[j], W1[j * 48 + tid], a);
        h1s[tid] = tanhf(a) + h0s[(tid < 24) ? tid : (tid - 24)];
    }
    __syncthreads();

    if (tid < 96) {
        float a = B2[tid];
#pragma unroll
        for (int k = 0; k < 48; ++k)
            a = __builtin_fmaf(h1s[k], W2[k * 96 + tid], a);
        tab[(size_t)row * 96 + tid] = (f16)(tanhf(a) + h1s[(tid < 48) ? tid : (tid - 48)]);
    }
}

// ---------------- main: lerp LUT + fused dd-contraction, all in registers ----------------
// rows r: 0..45 type0 (s=r), 46/47 pad; 48..139 type1 (s=r-2), 140..143 pad.
// 9 row-tiles of 16; wave w (of 3) owns tiles {w, w+3, w+6}.
// lane = (lhi, l15): lhi*4+rg = row-in-tile, l15 = e-pair index (e = c*32 + 2*l15 + {0,1}).
__global__ __launch_bounds__(192, 4)
void emb_main(const float* __restrict__ dmat, const f16* __restrict__ tab,
              int nseg, float scale, float offs,
              float* __restrict__ out)
{
    __shared__ float DD[144 * 4];       // [r][4] f32, pads zero (wave-private fill/use)
    __shared__ float Y2s[3 * 4 * 96];   // per-wave Y partials [w][d][e]

    const int tid = threadIdx.x, n = blockIdx.x;
    const int w = tid >> 6, lane = tid & 63;
    const int l15 = lane & 15, lhi = lane >> 4;

    // DD fill: wave w fills the 48 rows of its own 3 tiles
    if (lane < 48) {
        const int t = w + 3 * (lane >> 4);
        const int r = t * 16 + (lane & 15);
        const bool t0 = (t < 3);
        const int  s  = t0 ? r : (r - 2);
        const bool ok = t0 ? (r < 46) : (r < 140);
        float4 v = make_float4(0.f, 0.f, 0.f, 0.f);
        if (ok) v = *reinterpret_cast<const float4*>(dmat + (size_t)n * 552 + s * 4);
        *reinterpret_cast<float4*>(&DD[r * 4]) = v;
    }

    float yp[24];                        // [c][ep][d]
#pragma unroll
    for (int i = 0; i < 24; ++i) yp[i] = 0.f;

    const float clampHi = (float)nseg - 0.5f;
    const int rowU32 = 48;               // 96 halves per table row

    for (int t = w; t < 9; t += 3) {
        const int tyt = (t >= 3);
        const uint32_t* __restrict__ tb =
            reinterpret_cast<const uint32_t*>(tab + (size_t)tyt * (nseg + 1) * 96);

        int irow[4]; float fr[4]; float4 dd4[4];
#pragma unroll
        for (int rg = 0; rg < 4; ++rg) {
            const int r = t * 16 + lhi * 4 + rg;
            const float x = DD[r * 4];                    // 16-lane LDS broadcast
            float u = __builtin_fmaf(x, scale, offs);
            u = fminf(fmaxf(u, 0.f), clampHi);
            const int i = (int)u;
            irow[rg] = i * rowU32;
            fr[rg]   = u - (float)i;
            dd4[rg]  = *reinterpret_cast<const float4*>(&DD[r * 4]);
        }

#pragma unroll
        for (int c = 0; c < 3; ++c) {
#pragma unroll
            for (int rg = 0; rg < 4; ++rg) {
                const uint32_t* p = tb + irow[rg] + c * 16 + l15;
                const uint32_t alo = p[0];                 // row i,  e-pair
                const uint32_t ahi = p[rowU32];            // row i+1, e-pair
                const __half2 lo2 = *reinterpret_cast<const __half2*>(&alo);
                const __half2 hi2 = *reinterpret_cast<const __half2*>(&ahi);
                const float2 lo = __half22float2(lo2);
                const float2 hi = __half22float2(hi2);
                const float g0 = __builtin_fmaf(fr[rg], hi.x - lo.x, lo.x);
                const float g1 = __builtin_fmaf(fr[rg], hi.y - lo.y, lo.y);
                const int b = c * 8;
                yp[b + 0] = __builtin_fmaf(dd4[rg].x, g0, yp[b + 0]);
                yp[b + 1] = __builtin_fmaf(dd4[rg].y, g0, yp[b + 1]);
                yp[b + 2] = __builtin_fmaf(dd4[rg].z, g0, yp[b + 2]);
                yp[b + 3] = __builtin_fmaf(dd4[rg].w, g0, yp[b + 3]);
                yp[b + 4] = __builtin_fmaf(dd4[rg].x, g1, yp[b + 4]);
                yp[b + 5] = __builtin_fmaf(dd4[rg].y, g1, yp[b + 5]);
                yp[b + 6] = __builtin_fmaf(dd4[rg].z, g1, yp[b + 6]);
                yp[b + 7] = __builtin_fmaf(dd4[rg].w, g1, yp[b + 7]);
            }
        }
    }

    // reduce over the 4 lhi row-groups
#pragma unroll
    for (int i = 0; i < 24; ++i) {
        float v = yp[i];
        v += __shfl_xor(v, 16);
        v += __shfl_xor(v, 32);
        yp[i] = v;
    }
    if (lhi == 0) {
#pragma unroll
        for (int c = 0; c < 3; ++c)
#pragma unroll
            for (int d = 0; d < 4; ++d) {
                const float2 v2 = make_float2(yp[c * 8 + d], yp[c * 8 + 4 + d]);
                *reinterpret_cast<float2*>(&Y2s[w * 384 + d * 96 + c * 32 + 2 * l15]) = v2;
            }
    }
    __syncthreads();

    // stage 4: xs = (sum_w Y)/138; res[e][k] = sum_d xs[d][e]*xs[d][k]
    if (tid < 96) {
        constexpr float inv = 1.0f / 138.0f;
        const float x0 = (Y2s[tid]       + Y2s[384 + tid]       + Y2s[768 + tid])       * inv;
        const float x1 = (Y2s[96 + tid]  + Y2s[384 + 96 + tid]  + Y2s[768 + 96 + tid])  * inv;
        const float x2 = (Y2s[192 + tid] + Y2s[384 + 192 + tid] + Y2s[768 + 192 + tid]) * inv;
        const float x3 = (Y2s[288 + tid] + Y2s[384 + 288 + tid] + Y2s[768 + 288 + tid]) * inv;
        float rv[8];
#pragma unroll
        for (int k = 0; k < 8; ++k) {   // same-address reads -> LDS broadcast
            const float k0 = (Y2s[k]       + Y2s[384 + k]       + Y2s[768 + k])       * inv;
            const float k1 = (Y2s[96 + k]  + Y2s[384 + 96 + k]  + Y2s[768 + 96 + k])  * inv;
            const float k2 = (Y2s[192 + k] + Y2s[384 + 192 + k] + Y2s[768 + 192 + k]) * inv;
            const float k3 = (Y2s[288 + k] + Y2s[384 + 288 + k] + Y2s[768 + 288 + k]) * inv;
            float rr = x0 * k0;
            rr = __builtin_fmaf(x1, k1, rr);
            rr = __builtin_fmaf(x2, k2, rr);
            rr = __builtin_fmaf(x3, k3, rr);
            rv[k] = rr;
        }
        float* op = out + (size_t)n * 768 + tid * 8;
        *reinterpret_cast<float4*>(op)     = make_float4(rv[0], rv[1], rv[2], rv[3]);
        *reinterpret_cast<float4*>(op + 4) = make_float4(rv[4], rv[5], rv[6], rv[7]);
    }
}

extern "C" void kernel_launch(void* const* d_in, const int* in_sizes, int n_in,
                              void* d_out, int out_size, void* d_ws, size_t ws_size,
                              hipStream_t stream)
{
    const float* dmat = (const float*)d_in[0];
    const int n_atoms = in_sizes[0] / 552;   // 6144

    // largest table that fits ws: 2 types x (nseg+1) rows x 96 f16 (never overflows ws)
    int nseg = 2048;
    while ((size_t)2 * (size_t)(nseg + 1) * 96 * sizeof(f16) > ws_size && nseg > 16)
        nseg >>= 1;
    const float xmin = -8.f, xmax = 8.f;
    const float h     = (xmax - xmin) / (float)nseg;
    const float scale = (float)nseg / (xmax - xmin);
    const float offs  = -xmin * scale;
    f16* tab = (f16*)d_ws;

    const int rows2 = 2 * (nseg + 1);
    build_table<<<rows2, 128, 0, stream>>>(
        (const float*)d_in[1],  (const float*)d_in[2],
        (const float*)d_in[3],  (const float*)d_in[4],
        (const float*)d_in[5],  (const float*)d_in[6],
        (const float*)d_in[7],  (const float*)d_in[8],
        (const float*)d_in[9],  (const float*)d_in[10],
        (const float*)d_in[11], (const float*)d_in[12],
        tab, nseg, xmin, h);

    emb_main<<<n_atoms, 192, 0, stream>>>(dmat, tab, nseg, scale, offs, (float*)d_out);
}

// Round 9
// 40.391 us; speedup vs baseline: 2.7402x; 1.0143x over previous
//
#include <hip/hip_runtime.h>
#include <hip/hip_fp16.h>

typedef _Float16 f16;

// ---------------- one-time LUT build: g_ty(x) on a uniform grid ----------------
// 8 ROWS PER BLOCK (128 threads), blockIdx.y = type. Weight columns hoisted to
// registers and amortized over the 8 rows; layers chained via LDS + barriers.
// No cross-lane shuffles (R6 failure mode excluded). Exact f32 tanhf MLP.
__global__ __launch_bounds__(128)
void build_table(const float* __restrict__ w00, const float* __restrict__ b00,
                 const float* __restrict__ w01, const float* __restrict__ b01,
                 const float* __restrict__ w02, const float* __restrict__ b02,
                 const float* __restrict__ w10, const float* __restrict__ b10,
                 const float* __restrict__ w11, const float* __restrict__ b11,
                 const float* __restrict__ w12, const float* __restrict__ b12,
                 f16* __restrict__ tab, int rowsPerType, float xmin, float h)
{
    __shared__ float h0s[8][24];
    __shared__ float h1s[8][48];

    const int ty  = blockIdx.y;
    const int r0  = blockIdx.x * 8;
    const int tid = threadIdx.x;

    const float* __restrict__ W0 = ty ? w10 : w00;
    const float* __restrict__ B0 = ty ? b10 : b00;
    const float* __restrict__ W1 = ty ? w11 : w01;
    const float* __restrict__ B1 = ty ? b11 : b01;
    const float* __restrict__ W2 = ty ? w12 : w02;
    const float* __restrict__ B2 = ty ? b12 : b02;

    // phase 1: h0[q][j] for 8 rows x 24 units (192 tasks over 128 threads)
#pragma unroll
    for (int p = 0; p < 2; ++p) {
        const int idx = p * 128 + tid;
        if (idx < 192) {
            const int q = idx / 24, j = idx - q * 24;
            const float x = __builtin_fmaf((float)(r0 + q), h, xmin);
            h0s[q][j] = tanhf(__builtin_fmaf(x, W0[j], B0[j]));
        }
    }
    __syncthreads();

    // phase 2: h1[q][k]; thread = (half, k), W1 column in 24 registers, 4 rows each
    if (tid < 96) {
        const int half = tid / 48, k = tid - half * 48;
        float w1c[24];
#pragma unroll
        for (int j = 0; j < 24; ++j) w1c[j] = W1[j * 48 + k];
        const float bk = B1[k];
        const int km = (k < 24) ? k : (k - 24);
#pragma unroll
        for (int qq = 0; qq < 4; ++qq) {
            const int q = half * 4 + qq;
            float a = bk;
#pragma unroll
            for (int j = 0; j < 24; ++j)
                a = __builtin_fmaf(h0s[q][j], w1c[j], a);
            h1s[q][k] = tanhf(a) + h0s[q][km];
        }
    }
    __syncthreads();

    // phase 3: g[q][e]; thread = e, W2 column in 48 registers, loops 8 rows
    if (tid < 96) {
        const int e = tid;
        float w2c[48];
#pragma unroll
        for (int k = 0; k < 48; ++k) w2c[k] = W2[k * 96 + e];
        const float be = B2[e];
        const int em = (e < 48) ? e : (e - 48);
#pragma unroll
        for (int q = 0; q < 8; ++q) {
            if (r0 + q < rowsPerType) {
                float a = be;
#pragma unroll
                for (int k = 0; k < 48; ++k)
                    a = __builtin_fmaf(h1s[q][k], w2c[k], a);
                tab[((size_t)ty * rowsPerType + r0 + q) * 96 + e] = (f16)(tanhf(a) + h1s[q][em]);
            }
        }
    }
}

// ---------------- main: lerp LUT + fused dd-contraction, all in registers ----------------
// rows r: 0..45 type0 (s=r), 46/47 pad; 48..139 type1 (s=r-2), 140..143 pad.
// 9 row-tiles of 16; wave w (of 3) owns tiles {w, w+3, w+6}.
// lane = (lhi, l15): lhi*4+rg = row-in-tile, l15 = e-pair index (e = c*32 + 2*l15 + {0,1}).
__global__ __launch_bounds__(192, 4)
void emb_main(const float* __restrict__ dmat, const f16* __restrict__ tab,
              int nseg, float scale, float offs,
              float* __restrict__ out)
{
    __shared__ float DD[144 * 4];       // [r][4] f32, pads zero (wave-private fill/use)
    __shared__ float Y2s[3 * 4 * 96];   // per-wave Y partials [w][d][e]

    const int tid = threadIdx.x, n = blockIdx.x;
    const int w = tid >> 6, lane = tid & 63;
    const int l15 = lane & 15, lhi = lane >> 4;

    // DD fill: wave w fills the 48 rows of its own 3 tiles
    if (lane < 48) {
        const int t = w + 3 * (lane >> 4);
        const int r = t * 16 + (lane & 15);
        const bool t0 = (t < 3);
        const int  s  = t0 ? r : (r - 2);
        const bool ok = t0 ? (r < 46) : (r < 140);
        float4 v = make_float4(0.f, 0.f, 0.f, 0.f);
        if (ok) v = *reinterpret_cast<const float4*>(dmat + (size_t)n * 552 + s * 4);
        *reinterpret_cast<float4*>(&DD[r * 4]) = v;
    }

    float yp[24];                        // [c][ep][d]
#pragma unroll
    for (int i = 0; i < 24; ++i) yp[i] = 0.f;

    const float clampHi = (float)nseg - 0.5f;
    const int rowU32 = 48;               // 96 halves per table row

    for (int t = w; t < 9; t += 3) {
        const int tyt = (t >= 3);
        const uint32_t* __restrict__ tb =
            reinterpret_cast<const uint32_t*>(tab + (size_t)tyt * (nseg + 1) * 96);

        int irow[4]; float fr[4]; float4 dd4[4];
#pragma unroll
        for (int rg = 0; rg < 4; ++rg) {
            const int r = t * 16 + lhi * 4 + rg;
            const float x = DD[r * 4];                    // 16-lane LDS broadcast
            float u = __builtin_fmaf(x, scale, offs);
            u = fminf(fmaxf(u, 0.f), clampHi);
            const int i = (int)u;
            irow[rg] = i * rowU32;
            fr[rg]   = u - (float)i;
            dd4[rg]  = *reinterpret_cast<const float4*>(&DD[r * 4]);
        }

#pragma unroll
        for (int c = 0; c < 3; ++c) {
#pragma unroll
            for (int rg = 0; rg < 4; ++rg) {
                const uint32_t* p = tb + irow[rg] + c * 16 + l15;
                const uint32_t alo = p[0];                 // row i,  e-pair
                const uint32_t ahi = p[rowU32];            // row i+1, e-pair
                const __half2 lo2 = *reinterpret_cast<const __half2*>(&alo);
                const __half2 hi2 = *reinterpret_cast<const __half2*>(&ahi);
                const float2 lo = __half22float2(lo2);
                const float2 hi = __half22float2(hi2);
                const float g0 = __builtin_fmaf(fr[rg], hi.x - lo.x, lo.x);
                const float g1 = __builtin_fmaf(fr[rg], hi.y - lo.y, lo.y);
                const int b = c * 8;
                yp[b + 0] = __builtin_fmaf(dd4[rg].x, g0, yp[b + 0]);
                yp[b + 1] = __builtin_fmaf(dd4[rg].y, g0, yp[b + 1]);
                yp[b + 2] = __builtin_fmaf(dd4[rg].z, g0, yp[b + 2]);
                yp[b + 3] = __builtin_fmaf(dd4[rg].w, g0, yp[b + 3]);
                yp[b + 4] = __builtin_fmaf(dd4[rg].x, g1, yp[b + 4]);
                yp[b + 5] = __builtin_fmaf(dd4[rg].y, g1, yp[b + 5]);
                yp[b + 6] = __builtin_fmaf(dd4[rg].z, g1, yp[b + 6]);
                yp[b + 7] = __builtin_fmaf(dd4[rg].w, g1, yp[b + 7]);
            }
        }
    }

    // reduce over the 4 lhi row-groups
#pragma unroll
    for (int i = 0; i < 24; ++i) {
        float v = yp[i];
        v += __shfl_xor(v, 16);
        v += __shfl_xor(v, 32);
        yp[i] = v;
    }
    if (lhi == 0) {
#pragma unroll
        for (int c = 0; c < 3; ++c)
#pragma unroll
            for (int d = 0; d < 4; ++d) {
                const float2 v2 = make_float2(yp[c * 8 + d], yp[c * 8 + 4 + d]);
                *reinterpret_cast<float2*>(&Y2s[w * 384 + d * 96 + c * 32 + 2 * l15]) = v2;
            }
    }
    __syncthreads();

    // stage 4: xs = (sum_w Y)/138; res[e][k] = sum_d xs[d][e]*xs[d][k]
    if (tid < 96) {
        constexpr float inv = 1.0f / 138.0f;
        const float x0 = (Y2s[tid]       + Y2s[384 + tid]       + Y2s[768 + tid])       * inv;
        const float x1 = (Y2s[96 + tid]  + Y2s[384 + 96 + tid]  + Y2s[768 + 96 + tid])  * inv;
        const float x2 = (Y2s[192 + tid] + Y2s[384 + 192 + tid] + Y2s[768 + 192 + tid]) * inv;
        const float x3 = (Y2s[288 + tid] + Y2s[384 + 288 + tid] + Y2s[768 + 288 + tid]) * inv;
        float rv[8];
#pragma unroll
        for (int k = 0; k < 8; ++k) {   // same-address reads -> LDS broadcast
            const float k0 = (Y2s[k]       + Y2s[384 + k]       + Y2s[768 + k])       * inv;
            const float k1 = (Y2s[96 + k]  + Y2s[384 + 96 + k]  + Y2s[768 + 96 + k])  * inv;
            const float k2 = (Y2s[192 + k] + Y2s[384 + 192 + k] + Y2s[768 + 192 + k]) * inv;
            const float k3 = (Y2s[288 + k] + Y2s[384 + 288 + k] + Y2s[768 + 288 + k]) * inv;
            float rr = x0 * k0;
            rr = __builtin_fmaf(x1, k1, rr);
            rr = __builtin_fmaf(x2, k2, rr);
            rr = __builtin_fmaf(x3, k3, rr);
            rv[k] = rr;
        }
        float* op = out + (size_t)n * 768 + tid * 8;
        *reinterpret_cast<float4*>(op)     = make_float4(rv[0], rv[1], rv[2], rv[3]);
        *reinterpret_cast<float4*>(op + 4) = make_float4(rv[4], rv[5], rv[6], rv[7]);
    }
}

extern "C" void kernel_launch(void* const* d_in, const int* in_sizes, int n_in,
                              void* d_out, int out_size, void* d_ws, size_t ws_size,
                              hipStream_t stream)
{
    const float* dmat = (const float*)d_in[0];
    const int n_atoms = in_sizes[0] / 552;   // 6144

    // table: 2 types x (nseg+1) rows x 96 f16; cap nseg at 1024 (lerp err ~1e-4)
    int nseg = 1024;
    while ((size_t)2 * (size_t)(nseg + 1) * 96 * sizeof(f16) > ws_size && nseg > 16)
        nseg >>= 1;
    const float xmin = -8.f, xmax = 8.f;
    const float h     = (xmax - xmin) / (float)nseg;
    const float scale = (float)nseg / (xmax - xmin);
    const float offs  = -xmin * scale;
    f16* tab = (f16*)d_ws;

    const int rowsPerType = nseg + 1;
    dim3 bgrid((rowsPerType + 7) / 8, 2);
    build_table<<<bgrid, 128, 0, stream>>>(
        (const float*)d_in[1],  (const float*)d_in[2],
        (const float*)d_in[3],  (const float*)d_in[4],
        (const float*)d_in[5],  (const float*)d_in[6],
        (const float*)d_in[7],  (const float*)d_in[8],
        (const float*)d_in[9],  (const float*)d_in[10],
        (const float*)d_in[11], (const float*)d_in[12],
        tab, rowsPerType, xmin, h);

    emb_main<<<n_atoms, 192, 0, stream>>>(dmat, tab, nseg, scale, offs, (float*)d_out);
}